// Round 19
// baseline (22.233 us; speedup 1.0000x reference)
//
#include <hip/hip_runtime.h>
#include <hip/hip_bf16.h>

// Problem constants (from reference)
#define T_LEN 2048
#define D_DIM 64
#define K_CH  8
#define B_SZ  8

// Redundant-prefix single kernel, full chip, full coalescing:
// 256 blocks = (b, k, tq): block owns out t-range [tq*512,(tq+1)*512) and
// RECOMPUTES its init state from h[0, tq*512) (no cross-block deps).
// 1024 thr = 16 waves x 64 lanes; lane = d -> every load/store instruction
// is 256B contiguous per wave (R15 had 4x64B scattered sectors).
// bid&7=b pins each sequence's 32 blocks to one XCD -> prefix re-reads are
// L2-served (h[b] = 512KB << 4MB XCD L2).
#define TOUT 512               // out timesteps per block (T_LEN/4)
#define SUB 32                 // out timesteps per wave (TOUT/16)

__device__ __forceinline__ float2 cmul(float2 a, float2 b) {
    return make_float2(a.x * b.x - a.y * b.y, a.x * b.y + a.y * b.x);
}
__device__ __forceinline__ float2 cadd(float2 a, float2 b) {
    return make_float2(a.x + b.x, a.y + b.y);
}

__global__ __launch_bounds__(1024) void s4d_one(
    const float* __restrict__ h,
    const float* __restrict__ log_neg_re,
    const float* __restrict__ imag,
    const float* __restrict__ B_proj,
    const float* __restrict__ log_dt,
    float* __restrict__ out)
{
    const int bid = blockIdx.x;          // 256 = tq(4) x k(8) x b(8)
    const int b  = bid & 7;              // bid%8=b -> one XCD per sequence
    const int k  = (bid >> 3) & 7;
    const int tq = bid >> 6;             // 0..3 out t-quarter
    const int w  = threadIdx.x >> 6;     // 0..15 wave
    const int d  = threadIdx.x & 63;     // lane = d (full coalescing)

    // ---- per-k constants ----
    const float dt = expf(log_dt[0]);
    const float re = -expf(log_neg_re[k]);
    const float im = imag[k];
    const float mag = expf(re * dt);
    const float2 A  = make_float2(mag * cosf(im * dt), mag * sinf(im * dt));
    const float2 A2 = cmul(A, A);

    const float mag32 = expf(re * dt * 32.f);
    const float ang32 = im * dt * 32.f;
    const float2 a32 = make_float2(mag32 * cosf(ang32), mag32 * sinf(ang32));
    // aPS = A^(tq*32), block-uniform small loop
    float2 aPS = make_float2(1.f, 0.f);
    for (int i = 0; i < tq; ++i) aPS = cmul(aPS, a32);

    // C2 = 2 * B_proj * (A-1)/eig
    const float inv = 1.f / (re * re + im * im);
    const float2 num = make_float2(A.x - 1.f, A.y);
    const float bp = B_proj[k];
    const float2 C2v = make_float2(2.f * bp * (num.x * re + num.y * im) * inv,
                                   2.f * bp * (num.y * re - num.x * im) * inv);

    // ---- phase A: streamed prefix-slice carry over PS = tq*32 steps ----
    // wave w consumes h[w*PS .. (w+1)*PS): Cpre = sum_j A^{PS-1-j} h[..+j]
    const int PS = tq * 32;              // 0, 32, 64, 96 (block-uniform)
    {
    }
    const float* pp = h + ((size_t)b * T_LEN + (size_t)w * PS) * D_DIM + d;
    float2 ce = {0.f, 0.f}, co = {0.f, 0.f};
    #pragma unroll 8
    for (int m = 0; m < PS / 2; ++m) {   // <= 48 iters, 256B/wave loads
        float he = pp[(size_t)(2 * m) * D_DIM];
        float ho = pp[(size_t)(2 * m + 1) * D_DIM];
        ce = cmul(A2, ce); ce.x += he;
        co = cmul(A2, co); co.x += ho;
    }
    const float2 Cpre = cadd(cmul(A, ce), co);

    // ---- phase B: out-slice h into registers + 32-step carry ----
    const int t0 = tq * TOUT + w * SUB;
    const float* hp = h + ((size_t)b * T_LEN + t0) * D_DIM + d;
    float hv[SUB];
    #pragma unroll
    for (int j = 0; j < SUB; ++j) hv[j] = hp[(size_t)j * D_DIM];  // 256B/wave

    float2 ce2 = {0.f, 0.f}, co2 = {0.f, 0.f};
    #pragma unroll
    for (int m = 0; m < SUB / 2; ++m) {
        ce2 = cmul(A2, ce2); ce2.x += hv[2 * m];
        co2 = cmul(A2, co2); co2.x += hv[2 * m + 1];
    }
    const float2 Cout = cadd(cmul(A, ce2), co2);

    // ---- publish carries, one barrier ----
    __shared__ float2 smP[16][D_DIM];
    __shared__ float2 smO[16][D_DIM];
    smP[w][d] = Cpre;
    smO[w][d] = Cout;
    __syncthreads();

    // ---- X0 = state at tq*512: Horner over 16 prefix carries, step aPS ----
    float2 pv[16];
    #pragma unroll
    for (int v = 0; v < 16; ++v) pv[v] = smP[v][d];
    float2 x = {0.f, 0.f};
    #pragma unroll
    for (int v = 0; v < 16; ++v) x = cadd(cmul(aPS, x), pv[v]);
    // (tq=0: aPS=1, all pv=0 -> x=0)

    // ---- wave init: x = a32^w * X0 + sum_{v<w} a32^{w-1-v} Cout_v ----
    float2 ov[15];
    #pragma unroll
    for (int v = 0; v < 15; ++v)         // wave-uniform guard, static index
        ov[v] = (v < w) ? smO[v][d] : make_float2(0.f, 0.f);
    #pragma unroll
    for (int v = 0; v < 15; ++v)
        if (v < w) x = cadd(cmul(a32, x), ov[v]);

    // ---- replay 32 steps from registers, 256B/wave contiguous stores ----
    float* op = out + (((size_t)b * T_LEN + t0) * K_CH + k) * D_DIM + d;
    #pragma unroll
    for (int j = 0; j < SUB; ++j) {
        x = cmul(A, x);
        x.x += hv[j];
        op[(size_t)j * (K_CH * D_DIM)] = C2v.x * x.x - C2v.y * x.y;
    }
}

extern "C" void kernel_launch(void* const* d_in, const int* in_sizes, int n_in,
                              void* d_out, int out_size, void* d_ws, size_t ws_size,
                              hipStream_t stream) {
    const float* h          = (const float*)d_in[0];
    const float* log_neg_re = (const float*)d_in[1];
    const float* imag       = (const float*)d_in[2];
    const float* B_proj     = (const float*)d_in[3];
    const float* log_dt     = (const float*)d_in[4];
    float* out = (float*)d_out;

    // One kernel, one graph node, 256 blocks (1/CU), 1024 threads.
    hipLaunchKernelGGL(s4d_one, dim3(256), dim3(1024), 0, stream,
                       h, log_neg_re, imag, B_proj, log_dt, out);
}

// Round 20
// 16.074 us; speedup vs baseline: 1.3832x; 1.3832x over previous
//
#include <hip/hip_runtime.h>
#include <hip/hip_bf16.h>

// Problem constants (from reference)
#define T_LEN 2048
#define D_DIM 64
#define K_CH  8
#define B_SZ  8

// Single kernel, zero cross-block deps, full chip (R15 structure, FINAL):
// 256 blocks = (b, k, dq); block = 1024 thr = 16 waves x (s:4 sub-seg, d16:16).
// Rationale (measured over 19 rounds):
//  - intra-kernel cross-block sync costs >=15us on CDNA4 (R4/R6/R7) -> none.
//  - each extra graph node ~3.5us (R10) -> single kernel.
//  - full chip needs 256 blocks; block owns the full T-scan of its (b,k,dq)
//    slice -> 16-d blocks, 64B store sectors (L2 merges dq-sibling sectors;
//    full-256B variants R19/R12/R5 all regressed or were neutral).
//  - issue-all-loads-then-compute beats any explicit pipelining (R9/R13).
//  - chain-depth compression (R16), nt stores / y-transform (R17), extra
//    nodes (R10), redundant-prefix coalescing (R19): all regressed.
//  - bid&7=b pins each sequence to one XCD: h[b] (512KB) L2-resident.
#define SEG 128
#define SUB 32
#define NW (T_LEN / SEG)       // 16 waves

__device__ __forceinline__ float2 cmul(float2 a, float2 b) {
    return make_float2(a.x * b.x - a.y * b.y, a.x * b.y + a.y * b.x);
}
__device__ __forceinline__ float2 cadd(float2 a, float2 b) {
    return make_float2(a.x + b.x, a.y + b.y);
}
__device__ __forceinline__ float2 shfl2(float2 v, int lane) {
    return make_float2(__shfl(v.x, lane, 64), __shfl(v.y, lane, 64));
}

__global__ __launch_bounds__(1024) void s4d_one(
    const float* __restrict__ h,
    const float* __restrict__ log_neg_re,
    const float* __restrict__ imag,
    const float* __restrict__ B_proj,
    const float* __restrict__ log_dt,
    float* __restrict__ out)
{
    const int bid = blockIdx.x;          // 256 = dq(4) x k(8) x b(8)
    const int b  = bid & 7;              // bid%8=b -> sequence b on one XCD
    const int k  = (bid >> 3) & 7;
    const int dq = bid >> 6;             // 0..3
    const int w    = threadIdx.x >> 6;   // wave = t-segment
    const int lane = threadIdx.x & 63;
    const int s    = lane >> 4;          // 0..3: 32-step sub-segment
    const int d16  = lane & 15;
    const int d    = dq * 16 + d16;

    // ---- 1. issue all 32 h loads first (one exposed round trip) ----
    const int t0 = w * SEG + s * SUB;
    const float* hp = h + ((size_t)b * T_LEN + t0) * D_DIM + d;
    float hv[SUB];
    #pragma unroll
    for (int j = 0; j < SUB; ++j) hv[j] = hp[(size_t)j * D_DIM];

    // ---- 2. per-k constants (loads in flight) ----
    const float dt = expf(log_dt[0]);
    const float re = -expf(log_neg_re[k]);
    const float im = imag[k];
    const float mag = expf(re * dt);
    const float2 A  = make_float2(mag * cosf(im * dt), mag * sinf(im * dt));
    const float2 A2 = cmul(A, A);

    const float mag32 = expf(re * dt * 32.f);
    const float ang32 = im * dt * 32.f;
    const float2 a32  = make_float2(mag32 * cosf(ang32), mag32 * sinf(ang32));
    const float2 a64  = cmul(a32, a32);
    const float2 a96  = cmul(a64, a32);
    const float2 a128 = cmul(a64, a64);   // = A^SEG

    // C2 = 2 * B_proj * (A-1)/eig
    const float inv = 1.f / (re * re + im * im);
    const float2 num = make_float2(A.x - 1.f, A.y);
    const float bp = B_proj[k];
    const float2 C2v = make_float2(2.f * bp * (num.x * re + num.y * im) * inv,
                                   2.f * bp * (num.y * re - num.x * im) * inv);

    // ---- 3. phase A: 32-step sub-carry C = sum_j A^{31-j} hv[j] ----
    float2 ce = {0.f, 0.f}, co = {0.f, 0.f};
    #pragma unroll
    for (int m = 0; m < SUB / 2; ++m) {
        ce = cmul(A2, ce); ce.x += hv[2 * m];
        co = cmul(A2, co); co.x += hv[2 * m + 1];
    }
    const float2 C = cadd(cmul(A, ce), co);

    // ---- 4. wave-level: gather the 4 sub-carries for this (w,d16) ----
    const float2 c0 = shfl2(C, d16);
    const float2 c1 = shfl2(C, 16 + d16);
    const float2 c2 = shfl2(C, 32 + d16);
    const float2 c3 = shfl2(C, 48 + d16);
    // full 128-step segment carry: S = A^96 c0 + A^64 c1 + A^32 c2 + c3
    const float2 S = cadd(cadd(cmul(a96, c0), cmul(a64, c1)),
                          cadd(cmul(a32, c2), c3));

    // ---- 5. LDS scan across 16 waves: X_w = sum_{v<w} a128^{w-1-v} S_v ----
    __shared__ float2 sm[NW][16];
    if (s == 0) sm[w][d16] = S;
    __syncthreads();

    float2 sv[NW - 1];
    #pragma unroll
    for (int v = 0; v < NW - 1; ++v)    // wave-uniform guard, static index
        sv[v] = (v < w) ? sm[v][d16] : make_float2(0.f, 0.f);
    float2 x = {0.f, 0.f};
    #pragma unroll
    for (int v = 0; v < NW - 1; ++v)
        if (v < w) x = cadd(cmul(a128, x), sv[v]);

    // ---- 6. advance to this lane's sub-segment start ----
    if (s > 0) x = cadd(cmul(a32, x), c0);
    if (s > 1) x = cadd(cmul(a32, x), c1);
    if (s > 2) x = cadd(cmul(a32, x), c2);

    // ---- 7. replay 32 steps from registers, store ----
    float* op = out + (((size_t)b * T_LEN + t0) * K_CH + k) * D_DIM + d;
    #pragma unroll
    for (int j = 0; j < SUB; ++j) {
        x = cmul(A, x);
        x.x += hv[j];
        op[(size_t)j * (K_CH * D_DIM)] = C2v.x * x.x - C2v.y * x.y;  // 64B/16-lane sector
    }
}

extern "C" void kernel_launch(void* const* d_in, const int* in_sizes, int n_in,
                              void* d_out, int out_size, void* d_ws, size_t ws_size,
                              hipStream_t stream) {
    const float* h          = (const float*)d_in[0];
    const float* log_neg_re = (const float*)d_in[1];
    const float* imag       = (const float*)d_in[2];
    const float* B_proj     = (const float*)d_in[3];
    const float* log_dt     = (const float*)d_in[4];
    float* out = (float*)d_out;

    // One kernel, one graph node, 256 blocks (1/CU), 1024 threads.
    hipLaunchKernelGGL(s4d_one, dim3(256), dim3(1024), 0, stream,
                       h, log_neg_re, imag, B_proj, log_dt, out);
}